// Round 1
// baseline (742.972 us; speedup 1.0000x reference)
//
#include <hip/hip_runtime.h>
#include <stdint.h>
#include <stddef.h>

#define T_SEQ 2048
#define WINDOW_SZ 1024

typedef __attribute__((ext_vector_type(4))) float f32x4;
typedef __attribute__((ext_vector_type(8))) short s16x8;

__device__ inline unsigned short f2bf(float f) {
  union { float f; unsigned u; } v; v.f = f;
  unsigned u = v.u;
  return (unsigned short)((u + 0x7fffu + ((u >> 16) & 1u)) >> 16);
}

__device__ inline void gld_lds16(const unsigned short* g, unsigned short* l) {
  __builtin_amdgcn_global_load_lds((const __attribute__((address_space(1))) void*)g,
                                   (__attribute__((address_space(3))) void*)l, 16, 0, 0);
}

// ---------------- fp32 -> bf16 convert (vectorized) ----------------
__global__ __launch_bounds__(256) void cvt_bf16(const float* __restrict__ s,
                                                unsigned short* __restrict__ d, int n4) {
  int i = blockIdx.x * 256 + threadIdx.x;
  if (i >= n4) return;
  float4 v = ((const float4*)s)[i];
  ushort4 o;
  o.x = f2bf(v.x); o.y = f2bf(v.y); o.z = f2bf(v.z); o.w = f2bf(v.w);
  ((ushort4*)d)[i] = o;
}

// ---------------- bf16 GEMM: C[M,N] = A[M,K] @ Bt[N,K]^T (m97 pattern) ----------------
// 128x128 tile, BK=32, 4 waves, each wave 4x4 frags of 16x16x32.
__global__ __launch_bounds__(256) void gemm_bt(const unsigned short* __restrict__ A,
                                               const unsigned short* __restrict__ Bt,
                                               float* __restrict__ C, int M, int N, int K) {
  __shared__ unsigned short As[4096];  // 128 rows x 32 cols bf16
  __shared__ unsigned short Bs[4096];
  const int tid  = threadIdx.x;
  const int wave = tid >> 6, lane = tid & 63;
  const int quad = lane >> 4, l16 = lane & 15;
  const int m0 = blockIdx.y << 7, n0 = blockIdx.x << 7;
  const int wr = (wave >> 1) << 6;   // wave row offset (0/64)
  const int wc = (wave & 1) << 6;    // wave col offset (0/64)
  const int srow = tid >> 2;         // staging row 0..63
  const int scol = (tid & 3) << 3;   // staging col {0,8,16,24}

  f32x4 acc[4][4] = {};

  const unsigned short* pA0 = A  + (size_t)(m0 + srow) * K + scol;
  const unsigned short* pA1 = A  + (size_t)(m0 + 64 + srow) * K + scol;
  const unsigned short* pB0 = Bt + (size_t)(n0 + srow) * K + scol;
  const unsigned short* pB1 = Bt + (size_t)(n0 + 64 + srow) * K + scol;
  unsigned short* lA0 = As + wave * 512;          // wave-uniform LDS bases
  unsigned short* lA1 = As + 2048 + wave * 512;
  unsigned short* lB0 = Bs + wave * 512;
  unsigned short* lB1 = Bs + 2048 + wave * 512;

  for (int k0 = 0; k0 < K; k0 += 32) {
    gld_lds16(pA0 + k0, lA0);
    gld_lds16(pA1 + k0, lA1);
    gld_lds16(pB0 + k0, lB0);
    gld_lds16(pB1 + k0, lB1);
    __syncthreads();
    s16x8 af[4], bfr[4];
#pragma unroll
    for (int i = 0; i < 4; i++) {
      af[i]  = *(const s16x8*)&As[(wr + i * 16 + l16) * 32 + quad * 8];
      bfr[i] = *(const s16x8*)&Bs[(wc + i * 16 + l16) * 32 + quad * 8];
    }
#pragma unroll
    for (int mi = 0; mi < 4; mi++)
#pragma unroll
      for (int ni = 0; ni < 4; ni++)
        acc[mi][ni] = __builtin_amdgcn_mfma_f32_16x16x32_bf16(af[mi], bfr[ni], acc[mi][ni], 0, 0, 0);
    __syncthreads();
  }
#pragma unroll
  for (int mi = 0; mi < 4; mi++)
#pragma unroll
    for (int ni = 0; ni < 4; ni++) {
      int row = m0 + wr + mi * 16 + quad * 4;
      int col = n0 + wc + ni * 16 + l16;
#pragma unroll
      for (int r = 0; r < 4; r++)
        C[(size_t)(row + r) * N + col] = acc[mi][ni][r];
    }
}

// ---------------- fused RMSNorm + RoPE + layout (one block per token) ----------------
// qkv fp32 [T][6144] -> qr bf16 [32][T][128], kr bf16 [8][T][128], vt bf16 [8][128][T]
__global__ __launch_bounds__(256) void normrope(const float* __restrict__ qkv,
                                                const float* __restrict__ cosb,
                                                const float* __restrict__ sinb,
                                                const float* __restrict__ wq,
                                                const float* __restrict__ wk,
                                                unsigned short* __restrict__ qr,
                                                unsigned short* __restrict__ kr,
                                                unsigned short* __restrict__ vt) {
  const int t = blockIdx.x, tid = threadIdx.x;
  const float* row = qkv + (size_t)t * 6144;
  float sq = 0.f, sk = 0.f;
#pragma unroll
  for (int i = 0; i < 4; i++) {
    float4 v = ((const float4*)row)[tid + i * 256];
    sq += v.x * v.x + v.y * v.y + v.z * v.z + v.w * v.w;
  }
  {
    float4 v = ((const float4*)(row + 4096))[tid];
    sk = v.x * v.x + v.y * v.y + v.z * v.z + v.w * v.w;
  }
#pragma unroll
  for (int off = 32; off; off >>= 1) { sq += __shfl_xor(sq, off); sk += __shfl_xor(sk, off); }
  __shared__ float red[8];
  if ((tid & 63) == 0) { red[tid >> 6] = sq; red[4 + (tid >> 6)] = sk; }
  __syncthreads();
  sq = red[0] + red[1] + red[2] + red[3];
  sk = red[4] + red[5] + red[6] + red[7];
  const float rq = rsqrtf(sq * (1.f / 4096.f) + 1e-5f);
  const float rk = rsqrtf(sk * (1.f / 1024.f) + 1e-5f);
  // Q: rmsnorm over full 4096, then per-head rope
  for (int i = tid; i < 4096; i += 256) {
    int h = i >> 7, d = i & 127;
    int pd = (d < 64) ? d + 64 : d - 64;
    float val = row[i] * rq * wq[i];
    float pv  = row[(h << 7) + pd] * rq * wq[(h << 7) + pd];
    float rot = (d < 64) ? -pv : pv;
    float o = val * cosb[t * 128 + d] + rot * sinb[t * 128 + d];
    qr[(size_t)h * T_SEQ * 128 + t * 128 + d] = f2bf(o);
  }
  // K
  for (int i = tid; i < 1024; i += 256) {
    int g = i >> 7, d = i & 127;
    int pd = (d < 64) ? d + 64 : d - 64;
    float val = row[4096 + i] * rk * wk[i];
    float pv  = row[4096 + (g << 7) + pd] * rk * wk[(g << 7) + pd];
    float rot = (d < 64) ? -pv : pv;
    float o = val * cosb[t * 128 + d] + rot * sinb[t * 128 + d];
    kr[(size_t)g * T_SEQ * 128 + t * 128 + d] = f2bf(o);
  }
  // V transposed (time-minor) for PV B-frag contiguity
  for (int i = tid; i < 1024; i += 256) {
    int g = i >> 7, d = i & 127;
    vt[(size_t)g * 128 * T_SEQ + (size_t)d * T_SEQ + t] = f2bf(row[5120 + i]);
  }
}

// ---------------- flash attention, sliding window, 1 wave = 16 queries ----------------
__global__ __launch_bounds__(256) void attn(const unsigned short* __restrict__ Q,
                                            const unsigned short* __restrict__ Kb,
                                            const unsigned short* __restrict__ Vt,
                                            unsigned short* __restrict__ Y) {
  __shared__ float P[4][16 * 32];  // per-wave P round-trip buffer
  const int h = blockIdx.x >> 5;
  const int qb = blockIdx.x & 31;
  const int tid = threadIdx.x, wave = tid >> 6, lane = tid & 63;
  const int quad = lane >> 4, l16 = lane & 15;
  const int g = h >> 2;
  const int q0 = qb * 64 + wave * 16;
  const unsigned short* Qh = Q + (size_t)h * T_SEQ * 128;
  const unsigned short* Kg = Kb + (size_t)g * T_SEQ * 128;
  const unsigned short* Vg = Vt + (size_t)g * 128 * T_SEQ;
  float* Pw = P[wave];

  s16x8 aq[4];
#pragma unroll
  for (int ks = 0; ks < 4; ks++)
    aq[ks] = *(const s16x8*)&Qh[(size_t)(q0 + l16) * 128 + ks * 32 + quad * 8];

  f32x4 acc[8] = {};
  float mrow[4] = {-1e30f, -1e30f, -1e30f, -1e30f};
  float lrow[4] = {0.f, 0.f, 0.f, 0.f};
  const float scale = 0.08838834764831845f;  // 1/sqrt(128)

  int kk0 = q0 - (WINDOW_SZ - 1);
  if (kk0 < 0) kk0 = 0;
  kk0 &= ~31;
  for (int kk = kk0; kk <= q0 + 15; kk += 32) {
    // S = Q Kt : two 16x16 tiles over 32 keys
    f32x4 s0 = {0.f, 0.f, 0.f, 0.f}, s1 = {0.f, 0.f, 0.f, 0.f};
    int kr0 = kk + l16;      if (kr0 > T_SEQ - 1) kr0 = T_SEQ - 1;
    int kr1 = kk + 16 + l16; if (kr1 > T_SEQ - 1) kr1 = T_SEQ - 1;
#pragma unroll
    for (int ks = 0; ks < 4; ks++) {
      s16x8 b0 = *(const s16x8*)&Kg[(size_t)kr0 * 128 + ks * 32 + quad * 8];
      s16x8 b1 = *(const s16x8*)&Kg[(size_t)kr1 * 128 + ks * 32 + quad * 8];
      s0 = __builtin_amdgcn_mfma_f32_16x16x32_bf16(aq[ks], b0, s0, 0, 0, 0);
      s1 = __builtin_amdgcn_mfma_f32_16x16x32_bf16(aq[ks], b1, s1, 0, 0, 0);
    }
    // scale + window mask + online softmax (row = q0+quad*4+r, col = kk+{0,16}+l16)
    float p0[4], p1[4];
#pragma unroll
    for (int r = 0; r < 4; r++) {
      int irow = q0 + quad * 4 + r;
      int d0 = irow - (kk + l16), d1 = irow - (kk + 16 + l16);
      float v0 = s0[r] * scale, v1 = s1[r] * scale;
      if (d0 < 0 || d0 >= WINDOW_SZ) v0 = -1e30f;
      if (d1 < 0 || d1 >= WINDOW_SZ) v1 = -1e30f;
      p0[r] = v0; p1[r] = v1;
      float mx = fmaxf(v0, v1);
#pragma unroll
      for (int off = 8; off; off >>= 1) mx = fmaxf(mx, __shfl_xor(mx, off));
      float mnew = fmaxf(mrow[r], mx);
      float alpha = __expf(mrow[r] - mnew);  // both -1e30 -> exp(0)=1, l stays 0
      mrow[r] = mnew;
      float e0 = (p0[r] <= -1e29f) ? 0.f : __expf(p0[r] - mnew);
      float e1 = (p1[r] <= -1e29f) ? 0.f : __expf(p1[r] - mnew);
      p0[r] = e0; p1[r] = e1;
      float rs = e0 + e1;
#pragma unroll
      for (int off = 8; off; off >>= 1) rs += __shfl_xor(rs, off);
      lrow[r] = lrow[r] * alpha + rs;
#pragma unroll
      for (int n = 0; n < 8; n++) acc[n][r] *= alpha;
    }
    // P: C-layout -> A-layout via per-wave LDS (same-wave DS ops are in-order)
#pragma unroll
    for (int r = 0; r < 4; r++) {
      Pw[(quad * 4 + r) * 32 + l16] = p0[r];
      Pw[(quad * 4 + r) * 32 + 16 + l16] = p1[r];
    }
    s16x8 pa;
    {
      const float* src = &Pw[l16 * 32 + quad * 8];
      float4 f0 = *(const float4*)(src);
      float4 f1 = *(const float4*)(src + 4);
      pa[0] = (short)f2bf(f0.x); pa[1] = (short)f2bf(f0.y);
      pa[2] = (short)f2bf(f0.z); pa[3] = (short)f2bf(f0.w);
      pa[4] = (short)f2bf(f1.x); pa[5] = (short)f2bf(f1.y);
      pa[6] = (short)f2bf(f1.z); pa[7] = (short)f2bf(f1.w);
    }
    // O += P @ V  (V time-minor: contiguous 16B frags)
    int t0 = kk + quad * 8;
    if (t0 > T_SEQ - 8) t0 = T_SEQ - 8;  // safety; masked cols have p=0
#pragma unroll
    for (int n = 0; n < 8; n++) {
      s16x8 bv = *(const s16x8*)&Vg[(size_t)(n * 16 + l16) * T_SEQ + t0];
      acc[n] = __builtin_amdgcn_mfma_f32_16x16x32_bf16(pa, bv, acc[n], 0, 0, 0);
    }
  }
  // epilogue: O / l -> y bf16 [T][4096]
#pragma unroll
  for (int n = 0; n < 8; n++)
#pragma unroll
    for (int r = 0; r < 4; r++) {
      int irow = q0 + quad * 4 + r;
      float o = acc[n][r] / lrow[r];
      Y[(size_t)irow * 4096 + h * 128 + n * 16 + l16] = f2bf(o);
    }
}

extern "C" void kernel_launch(void* const* d_in, const int* in_sizes, int n_in,
                              void* d_out, int out_size, void* d_ws, size_t ws_size,
                              hipStream_t stream) {
  (void)in_sizes; (void)n_in; (void)out_size; (void)ws_size;
  const float* x     = (const float*)d_in[0];
  const float* cosb  = (const float*)d_in[1];
  const float* sinb  = (const float*)d_in[2];
  const float* Wqkv  = (const float*)d_in[3];
  const float* wq    = (const float*)d_in[4];
  const float* wk    = (const float*)d_in[5];
  const float* Wproj = (const float*)d_in[6];
  float* out = (float*)d_out;

  char* ws = (char*)d_ws;
  unsigned short* x_bf     = (unsigned short*)(ws);                 // 16 MB
  unsigned short* wqkv_bf  = (unsigned short*)(ws + 16777216);      // 48 MB
  unsigned short* wproj_bf = (unsigned short*)(ws + 67108864);      // 32 MB
  float*          qkv      = (float*)(ws + 100663296);              // 48 MB
  unsigned short* qr       = (unsigned short*)(ws + 150994944);     // 16 MB
  unsigned short* kr       = (unsigned short*)(ws + 167772160);     // 4 MB
  unsigned short* vt       = (unsigned short*)(ws + 171966464);     // 4 MB
  unsigned short* y        = (unsigned short*)(ws + 176160768);     // 16 MB

  cvt_bf16<<<(2097152 + 255) / 256, 256, 0, stream>>>(x, x_bf, 2097152);        // 2048*4096/4
  cvt_bf16<<<(6291456 + 255) / 256, 256, 0, stream>>>(Wqkv, wqkv_bf, 6291456);  // 6144*4096/4
  cvt_bf16<<<(4194304 + 255) / 256, 256, 0, stream>>>(Wproj, wproj_bf, 4194304);// 4096*4096/4
  gemm_bt<<<dim3(48, 16), 256, 0, stream>>>(x_bf, wqkv_bf, qkv, 2048, 6144, 4096);
  normrope<<<2048, 256, 0, stream>>>(qkv, cosb, sinb, wq, wk, qr, kr, vt);
  attn<<<1024, 256, 0, stream>>>(qr, kr, vt, y);
  gemm_bt<<<dim3(32, 16), 256, 0, stream>>>(y, wproj_bf, out, 2048, 4096, 4096);
}